// Round 11
// baseline (259.532 us; speedup 1.0000x reference)
//
#include <hip/hip_runtime.h>

// EnvironmentalAugmentations: pink = AR(1) scan of white noise (a=0.99, b=0.01),
// mixed = waveform + 0.05*pink, out = mixed / max(|mixed|) if max > 1 else mixed.
// Shapes: (256 channels, 220500 samples), f32 in / f32 out.
//
// Learned R1-R9: the only structure that streams near the copy ceiling is the
// R8 "apply" shape: one wave per INDEPENDENT segment, loads issued at iteration
// top, shallow dependent chains, no barriers, no cross-iteration state.
// R10/R11: fused apply with per-segment warm-up:
//   - segment 2048 + private 512-sample warm-up (0.99^512=5.9e-3 -> out err ~6e-5)
//   - all 18 float4 loads issued up front; 5 independent serial8+wave_scan8
//     pipelines; only 4 scalar FMAs chain state across sub-blocks
//   - non-temporal loads for white/waveform (streamed once) so LLC keeps the
//     out lines -> scale pass reads from LLC; nt stores in scale (final data)
// R11 fixes R10's compile error: __builtin_nontemporal_* requires a native
// vector type, not HIP_vector_type -> use ext_vector_type(4).

#define TLEN 220500
#define CHANNELS 256

constexpr int SEGL = 2048;                        // samples per segment (1 wave)
constexpr int WUP  = 512;                         // warm-up samples
constexpr int SPC  = (TLEN + SEGL - 1) / SEGL;    // 108 segments per channel
constexpr int NSEG = SPC * CHANNELS;              // 27648 segments
constexpr int NB   = NSEG / 4;                    // 6912 blocks (4 waves each)

constexpr float AC = 0.99f;
constexpr float BC = 0.01f;
constexpr float NL = 0.05f;

constexpr double dpow(double a, long n) { double r = 1.0; for (long i = 0; i < n; ++i) r *= a; return r; }

// wave scan multipliers at 8-sample granularity: 0.99^(8d)
constexpr float S8P0 = (float)dpow(0.99, 8);
constexpr float S8P1 = (float)dpow(0.99, 16);
constexpr float S8P2 = (float)dpow(0.99, 32);
constexpr float S8P3 = (float)dpow(0.99, 64);
constexpr float S8P4 = (float)dpow(0.99, 128);
constexpr float S8P5 = (float)dpow(0.99, 256);
constexpr float A512 = (float)dpow(0.99, 512);    // sub-block decay
constexpr float L2A8 = -0.11599655756609923f;     // 8 * log2(0.99)

// native vector type for nontemporal builtins (same layout as float4)
typedef float f4 __attribute__((ext_vector_type(4)));

__device__ __forceinline__ f4 ntld4(const float* p) {
    return __builtin_nontemporal_load(reinterpret_cast<const f4*>(p));
}
__device__ __forceinline__ void ntst4(float* p, f4 v) {
    __builtin_nontemporal_store(v, reinterpret_cast<f4*>(p));
}

__device__ __forceinline__ float wave_scan8(float f, int lane) {
    { float o = __shfl_up(f, 1,  64); if (lane >= 1)  f = fmaf(S8P0, o, f); }
    { float o = __shfl_up(f, 2,  64); if (lane >= 2)  f = fmaf(S8P1, o, f); }
    { float o = __shfl_up(f, 4,  64); if (lane >= 4)  f = fmaf(S8P2, o, f); }
    { float o = __shfl_up(f, 8,  64); if (lane >= 8)  f = fmaf(S8P3, o, f); }
    { float o = __shfl_up(f, 16, 64); if (lane >= 16) f = fmaf(S8P4, o, f); }
    { float o = __shfl_up(f, 32, 64); if (lane >= 32) f = fmaf(S8P5, o, f); }
    return f;
}

__device__ __forceinline__ float serial8(const f4& a, const f4& b) {
    float f = BC * a.x;
    f = fmaf(AC, f, BC * a.y);
    f = fmaf(AC, f, BC * a.z);
    f = fmaf(AC, f, BC * a.w);
    f = fmaf(AC, f, BC * b.x);
    f = fmaf(AC, f, BC * b.y);
    f = fmaf(AC, f, BC * b.z);
    f = fmaf(AC, f, BC * b.w);
    return f;
}

__global__ void init_max_kernel(unsigned int* gmax) { *gmax = 0u; }

// USE_ATOMIC=1 is the fallback (ws too small): atomicMax into gmax.
template <int USE_ATOMIC>
__global__ __launch_bounds__(256)
void fused_kernel(const float* __restrict__ waveform,
                  const float* __restrict__ white,
                  float* __restrict__ out,
                  unsigned int* __restrict__ gmax,
                  float* __restrict__ blockmax)
{
    __shared__ float sM[4];
    const int tid  = threadIdx.x;
    const int lane = tid & 63;
    const int wv   = tid >> 6;
    const int S    = blockIdx.x * 4 + wv;          // one segment per wave
    const int ch   = S / SPC;
    const int s    = S - ch * SPC;
    const size_t row = (size_t)ch * TLEN;
    const float* __restrict__ wrow = white + row;
    const float* __restrict__ arow = waveform + row;
    float* __restrict__ orow = out + row;
    const int seg0 = s * SEGL;
    const int l8   = 8 * lane;
    const float D8L = __builtin_exp2f((float)lane * L2A8);   // 0.99^(8*lane)
    const f4 z4 = {0.f, 0.f, 0.f, 0.f};

    // ---- issue ALL loads up front (18 float4, coalesced, non-temporal) ----
    f4 wu0 = z4, wu1 = z4;
    if (s > 0) {
        const float* wb = wrow + (seg0 - WUP) + l8;   // always in-bounds
        wu0 = ntld4(wb);
        wu1 = ntld4(wb + 4);
    }
    f4 Wa[4], Wb[4], Aa[4], Ab[4];
    #pragma unroll
    for (int p = 0; p < 4; ++p) {                     // compile-time p
        const int g = seg0 + p * 512 + l8;
        Wa[p] = z4; Wb[p] = z4; Aa[p] = z4; Ab[p] = z4;
        if (g < TLEN) {                               // g%4==0, TLEN%4==0
            Wa[p] = ntld4(wrow + g);
            Aa[p] = ntld4(arow + g);
        }
        if (g + 4 < TLEN) {
            Wb[p] = ntld4(wrow + g + 4);
            Ab[p] = ntld4(arow + g + 4);
        }
    }

    // ---- 5 independent scan pipelines (warm-up + 4 sub-blocks) ----
    float Tw = 0.f;
    if (s > 0) {
        float f = serial8(wu0, wu1);
        float p = wave_scan8(f, lane);
        Tw = __shfl(p, 63, 64);
    }
    float eB[4], T[4];
    #pragma unroll
    for (int p = 0; p < 4; ++p) {
        float f  = serial8(Wa[p], Wb[p]);
        float sc = wave_scan8(f, lane);
        float ex = __shfl_up(sc, 1, 64);
        eB[p] = (lane == 0) ? 0.f : ex;
        T[p]  = __shfl(sc, 63, 64);
    }

    // entry state: warm-up total, or w[0] for the very first segment
    // (E = w0 is exact: a*w0 + b*w0 = w0 reproduces pink[0] = w0)
    float E = (s > 0) ? Tw : __shfl(Wa[0].x, 0, 64);

    // ---- mix + store + max; only 4 scalar FMAs chain across sub-blocks ----
    float mx = 0.f;
    #pragma unroll
    for (int p = 0; p < 4; ++p) {
        float f = fmaf(D8L, E, eB[p]);               // lane entry state
        f4 ma, mb;
        f = fmaf(AC, f, BC * Wa[p].x); ma.x = fmaf(NL, f, Aa[p].x);
        f = fmaf(AC, f, BC * Wa[p].y); ma.y = fmaf(NL, f, Aa[p].y);
        f = fmaf(AC, f, BC * Wa[p].z); ma.z = fmaf(NL, f, Aa[p].z);
        f = fmaf(AC, f, BC * Wa[p].w); ma.w = fmaf(NL, f, Aa[p].w);
        f = fmaf(AC, f, BC * Wb[p].x); mb.x = fmaf(NL, f, Ab[p].x);
        f = fmaf(AC, f, BC * Wb[p].y); mb.y = fmaf(NL, f, Ab[p].y);
        f = fmaf(AC, f, BC * Wb[p].z); mb.z = fmaf(NL, f, Ab[p].z);
        f = fmaf(AC, f, BC * Wb[p].w); mb.w = fmaf(NL, f, Ab[p].w);

        const int g = seg0 + p * 512 + l8;
        if (g < TLEN) {                              // regular store: keep in LLC
            *reinterpret_cast<f4*>(orow + g) = ma;
            mx = fmaxf(mx, fmaxf(fmaxf(fabsf(ma.x), fabsf(ma.y)),
                                 fmaxf(fabsf(ma.z), fabsf(ma.w))));
        }
        if (g + 4 < TLEN) {
            *reinterpret_cast<f4*>(orow + g + 4) = mb;
            mx = fmaxf(mx, fmaxf(fmaxf(fabsf(mb.x), fabsf(mb.y)),
                                 fmaxf(fabsf(mb.z), fabsf(mb.w))));
        }
        E = fmaf(A512, E, T[p]);                     // advance sub-block state
    }

    // ---- block max ----
    #pragma unroll
    for (int d = 32; d >= 1; d >>= 1)
        mx = fmaxf(mx, __shfl_xor(mx, d, 64));
    if (lane == 0) sM[wv] = mx;
    __syncthreads();
    if (tid == 0) {
        float m = fmaxf(fmaxf(sM[0], sM[1]), fmaxf(sM[2], sM[3]));
        if (USE_ATOMIC) {
            atomicMax(gmax, __float_as_uint(m));     // values >= 0
        } else {
            blockmax[blockIdx.x] = m;
        }
    }
}

// reduce NB block maxima -> gmax (float bits as uint)
__global__ __launch_bounds__(256)
void reduce_max_kernel(const float* __restrict__ blockmax, unsigned int* __restrict__ gmax)
{
    __shared__ float sM[4];
    const int tid  = threadIdx.x;
    const int lane = tid & 63;
    const int wv   = tid >> 6;
    float mx = 0.f;
    for (int i = tid; i < NB; i += 256)
        mx = fmaxf(mx, blockmax[i]);
    #pragma unroll
    for (int d = 32; d >= 1; d >>= 1)
        mx = fmaxf(mx, __shfl_xor(mx, d, 64));
    if (lane == 0) sM[wv] = mx;
    __syncthreads();
    if (tid == 0)
        *gmax = __float_as_uint(fmaxf(fmaxf(sM[0], sM[1]), fmaxf(sM[2], sM[3])));
}

__global__ __launch_bounds__(256)
void scale_kernel(float* __restrict__ out, const unsigned int* __restrict__ gmax, int n4)
{
    const float m = __uint_as_float(*gmax);
    const float s = (m > 1.0f) ? (1.0f / m) : 1.0f;
    f4* p = reinterpret_cast<f4*>(out);
    int i = blockIdx.x * blockDim.x + threadIdx.x;
    const int stride = gridDim.x * blockDim.x;
    for (; i < n4; i += stride) {
        f4 v = p[i];                     // regular load: should hit LLC
        v.x *= s; v.y *= s; v.z *= s; v.w *= s;
        __builtin_nontemporal_store(v, &p[i]);   // final data: bypass LLC
    }
}

extern "C" void kernel_launch(void* const* d_in, const int* in_sizes, int n_in,
                              void* d_out, int out_size, void* d_ws, size_t ws_size,
                              hipStream_t stream)
{
    const float* waveform = (const float*)d_in[0];
    const float* white    = (const float*)d_in[1];
    float* out            = (float*)d_out;

    // ws layout: gmax @0 (256B reserved) | blockmax @256 (NB floats)
    unsigned int* gmax = (unsigned int*)d_ws;
    float* blockmax    = (float*)((char*)d_ws + 256);
    const bool ws_ok   = ws_size >= 256 + (size_t)NB * sizeof(float);

    const int n4 = out_size / 4;           // 14,112,000 float4s

    if (ws_ok) {
        hipLaunchKernelGGL((fused_kernel<0>), dim3(NB), dim3(256), 0, stream,
                           waveform, white, out, gmax, blockmax);
        hipLaunchKernelGGL(reduce_max_kernel, dim3(1), dim3(256), 0, stream,
                           blockmax, gmax);
    } else {
        hipLaunchKernelGGL(init_max_kernel, dim3(1), dim3(1), 0, stream, gmax);
        hipLaunchKernelGGL((fused_kernel<1>), dim3(NB), dim3(256), 0, stream,
                           waveform, white, out, gmax, blockmax);
    }
    hipLaunchKernelGGL(scale_kernel, dim3(3072), dim3(256), 0, stream,
                       out, gmax, n4);
}

// Round 12
// 232.754 us; speedup vs baseline: 1.1151x; 1.1151x over previous
//
#include <hip/hip_runtime.h>

// EnvironmentalAugmentations: pink = AR(1) scan of white noise (a=0.99, b=0.01),
// mixed = waveform + 0.05*pink, out = mixed / max(|mixed|) if max > 1 else mixed.
// Shapes: (256 channels, 220500 samples), f32 in / f32 out.
//
// R8 evidence: grid-stride PERSISTENT blocks (apply_kernel) -> 83% occ, 5.3 TB/s
// fabric. R11 evidence: same math in short-lived one-segment blocks -> 40% occ,
// 3.2 TB/s (dispatch gaps between block retirements).
// R12: R11 body (segment 2048 + private 512 warm-up, 0.99^512=5.9e-3 -> output
// err ~4e-3 << 2e-2 threshold; NT loads for streamed inputs) wrapped in a
// grid-stride loop over segments: 2048 persistent blocks, 3-4 segments/wave.

#define TLEN 220500
#define CHANNELS 256

constexpr int SEGL = 2048;                        // samples per segment (1 wave)
constexpr int WUP  = 512;                         // warm-up samples
constexpr int SPC  = (TLEN + SEGL - 1) / SEGL;    // 108 segments per channel
constexpr int NSEG = SPC * CHANNELS;              // 27648 segments
constexpr int NBLOCKS = 2048;                     // persistent blocks
constexpr int GRID_WAVES = NBLOCKS * 4;           // 8192 waves

constexpr float AC = 0.99f;
constexpr float BC = 0.01f;
constexpr float NL = 0.05f;

constexpr double dpow(double a, long n) { double r = 1.0; for (long i = 0; i < n; ++i) r *= a; return r; }

// wave scan multipliers at 8-sample granularity: 0.99^(8d)
constexpr float S8P0 = (float)dpow(0.99, 8);
constexpr float S8P1 = (float)dpow(0.99, 16);
constexpr float S8P2 = (float)dpow(0.99, 32);
constexpr float S8P3 = (float)dpow(0.99, 64);
constexpr float S8P4 = (float)dpow(0.99, 128);
constexpr float S8P5 = (float)dpow(0.99, 256);
constexpr float A512 = (float)dpow(0.99, 512);    // sub-block decay
constexpr float L2A8 = -0.11599655756609923f;     // 8 * log2(0.99)

// native vector type for nontemporal builtins (same layout as float4)
typedef float f4 __attribute__((ext_vector_type(4)));

__device__ __forceinline__ f4 ntld4(const float* p) {
    return __builtin_nontemporal_load(reinterpret_cast<const f4*>(p));
}

__device__ __forceinline__ float wave_scan8(float f, int lane) {
    { float o = __shfl_up(f, 1,  64); if (lane >= 1)  f = fmaf(S8P0, o, f); }
    { float o = __shfl_up(f, 2,  64); if (lane >= 2)  f = fmaf(S8P1, o, f); }
    { float o = __shfl_up(f, 4,  64); if (lane >= 4)  f = fmaf(S8P2, o, f); }
    { float o = __shfl_up(f, 8,  64); if (lane >= 8)  f = fmaf(S8P3, o, f); }
    { float o = __shfl_up(f, 16, 64); if (lane >= 16) f = fmaf(S8P4, o, f); }
    { float o = __shfl_up(f, 32, 64); if (lane >= 32) f = fmaf(S8P5, o, f); }
    return f;
}

__device__ __forceinline__ float serial8(const f4& a, const f4& b) {
    float f = BC * a.x;
    f = fmaf(AC, f, BC * a.y);
    f = fmaf(AC, f, BC * a.z);
    f = fmaf(AC, f, BC * a.w);
    f = fmaf(AC, f, BC * b.x);
    f = fmaf(AC, f, BC * b.y);
    f = fmaf(AC, f, BC * b.z);
    f = fmaf(AC, f, BC * b.w);
    return f;
}

__global__ void init_max_kernel(unsigned int* gmax) { *gmax = 0u; }

// USE_ATOMIC=1 is the fallback (ws too small): atomicMax into gmax.
template <int USE_ATOMIC>
__global__ __launch_bounds__(256)
void fused_kernel(const float* __restrict__ waveform,
                  const float* __restrict__ white,
                  float* __restrict__ out,
                  unsigned int* __restrict__ gmax,
                  float* __restrict__ blockmax)
{
    __shared__ float sM[4];
    const int tid  = threadIdx.x;
    const int lane = tid & 63;
    const int wv   = tid >> 6;
    const int l8   = 8 * lane;
    const float D8L = __builtin_exp2f((float)lane * L2A8);   // 0.99^(8*lane)
    const f4 z4 = {0.f, 0.f, 0.f, 0.f};

    float mx = 0.f;

    // ---- grid-stride over segments: persistent blocks, no redispatch ----
    for (int S = blockIdx.x * 4 + wv; S < NSEG; S += GRID_WAVES) {
        const int ch = S / SPC;
        const int s  = S - ch * SPC;
        const size_t row = (size_t)ch * TLEN;
        const float* __restrict__ wrow = white + row;
        const float* __restrict__ arow = waveform + row;
        float* __restrict__ orow = out + row;
        const int seg0 = s * SEGL;

        // ---- issue ALL loads up front (18 float4, coalesced, non-temporal) ----
        f4 wu0 = z4, wu1 = z4;
        if (s > 0) {
            const float* wb = wrow + (seg0 - WUP) + l8;   // always in-bounds
            wu0 = ntld4(wb);
            wu1 = ntld4(wb + 4);
        }
        f4 Wa[4], Wb[4], Aa[4], Ab[4];
        #pragma unroll
        for (int p = 0; p < 4; ++p) {                     // compile-time p
            const int g = seg0 + p * 512 + l8;
            Wa[p] = z4; Wb[p] = z4; Aa[p] = z4; Ab[p] = z4;
            if (g < TLEN) {                               // g%4==0, TLEN%4==0
                Wa[p] = ntld4(wrow + g);
                Aa[p] = ntld4(arow + g);
            }
            if (g + 4 < TLEN) {
                Wb[p] = ntld4(wrow + g + 4);
                Ab[p] = ntld4(arow + g + 4);
            }
        }

        // ---- 5 independent scan pipelines (warm-up + 4 sub-blocks) ----
        float Tw = 0.f;
        if (s > 0) {
            float f = serial8(wu0, wu1);
            float p = wave_scan8(f, lane);
            Tw = __shfl(p, 63, 64);
        }
        float eB[4], T[4];
        #pragma unroll
        for (int p = 0; p < 4; ++p) {
            float f  = serial8(Wa[p], Wb[p]);
            float sc = wave_scan8(f, lane);
            float ex = __shfl_up(sc, 1, 64);
            eB[p] = (lane == 0) ? 0.f : ex;
            T[p]  = __shfl(sc, 63, 64);
        }

        // entry state: warm-up total, or w[0] for the very first segment
        // (E = w0 is exact: a*w0 + b*w0 = w0 reproduces pink[0] = w0)
        float E = (s > 0) ? Tw : __shfl(Wa[0].x, 0, 64);

        // ---- mix + store + max; only 4 scalar FMAs chain across sub-blocks ----
        #pragma unroll
        for (int p = 0; p < 4; ++p) {
            float f = fmaf(D8L, E, eB[p]);               // lane entry state
            f4 ma, mb;
            f = fmaf(AC, f, BC * Wa[p].x); ma.x = fmaf(NL, f, Aa[p].x);
            f = fmaf(AC, f, BC * Wa[p].y); ma.y = fmaf(NL, f, Aa[p].y);
            f = fmaf(AC, f, BC * Wa[p].z); ma.z = fmaf(NL, f, Aa[p].z);
            f = fmaf(AC, f, BC * Wa[p].w); ma.w = fmaf(NL, f, Aa[p].w);
            f = fmaf(AC, f, BC * Wb[p].x); mb.x = fmaf(NL, f, Ab[p].x);
            f = fmaf(AC, f, BC * Wb[p].y); mb.y = fmaf(NL, f, Ab[p].y);
            f = fmaf(AC, f, BC * Wb[p].z); mb.z = fmaf(NL, f, Ab[p].z);
            f = fmaf(AC, f, BC * Wb[p].w); mb.w = fmaf(NL, f, Ab[p].w);

            const int g = seg0 + p * 512 + l8;
            if (g < TLEN) {                              // regular store: keep in LLC
                *reinterpret_cast<f4*>(orow + g) = ma;
                mx = fmaxf(mx, fmaxf(fmaxf(fabsf(ma.x), fabsf(ma.y)),
                                     fmaxf(fabsf(ma.z), fabsf(ma.w))));
            }
            if (g + 4 < TLEN) {
                *reinterpret_cast<f4*>(orow + g + 4) = mb;
                mx = fmaxf(mx, fmaxf(fmaxf(fabsf(mb.x), fabsf(mb.y)),
                                     fmaxf(fabsf(mb.z), fabsf(mb.w))));
            }
            E = fmaf(A512, E, T[p]);                     // advance sub-block state
        }
    }

    // ---- block max (once, after all iterations) ----
    #pragma unroll
    for (int d = 32; d >= 1; d >>= 1)
        mx = fmaxf(mx, __shfl_xor(mx, d, 64));
    if (lane == 0) sM[wv] = mx;
    __syncthreads();
    if (tid == 0) {
        float m = fmaxf(fmaxf(sM[0], sM[1]), fmaxf(sM[2], sM[3]));
        if (USE_ATOMIC) {
            atomicMax(gmax, __float_as_uint(m));         // values >= 0
        } else {
            blockmax[blockIdx.x] = m;
        }
    }
}

// reduce NBLOCKS block maxima -> gmax (float bits as uint)
__global__ __launch_bounds__(256)
void reduce_max_kernel(const float* __restrict__ blockmax, unsigned int* __restrict__ gmax)
{
    __shared__ float sM[4];
    const int tid  = threadIdx.x;
    const int lane = tid & 63;
    const int wv   = tid >> 6;
    float mx = 0.f;
    for (int i = tid; i < NBLOCKS; i += 256)
        mx = fmaxf(mx, blockmax[i]);
    #pragma unroll
    for (int d = 32; d >= 1; d >>= 1)
        mx = fmaxf(mx, __shfl_xor(mx, d, 64));
    if (lane == 0) sM[wv] = mx;
    __syncthreads();
    if (tid == 0)
        *gmax = __float_as_uint(fmaxf(fmaxf(sM[0], sM[1]), fmaxf(sM[2], sM[3])));
}

__global__ __launch_bounds__(256)
void scale_kernel(float* __restrict__ out, const unsigned int* __restrict__ gmax, int n4)
{
    const float m = __uint_as_float(*gmax);
    const float s = (m > 1.0f) ? (1.0f / m) : 1.0f;
    f4* p = reinterpret_cast<f4*>(out);
    int i = blockIdx.x * blockDim.x + threadIdx.x;
    const int stride = gridDim.x * blockDim.x;
    for (; i < n4; i += stride) {
        f4 v = p[i];                     // regular load: should hit LLC
        v.x *= s; v.y *= s; v.z *= s; v.w *= s;
        __builtin_nontemporal_store(v, &p[i]);   // final data: bypass LLC
    }
}

extern "C" void kernel_launch(void* const* d_in, const int* in_sizes, int n_in,
                              void* d_out, int out_size, void* d_ws, size_t ws_size,
                              hipStream_t stream)
{
    const float* waveform = (const float*)d_in[0];
    const float* white    = (const float*)d_in[1];
    float* out            = (float*)d_out;

    // ws layout: gmax @0 (256B reserved) | blockmax @256 (NBLOCKS floats)
    unsigned int* gmax = (unsigned int*)d_ws;
    float* blockmax    = (float*)((char*)d_ws + 256);
    const bool ws_ok   = ws_size >= 256 + (size_t)NBLOCKS * sizeof(float);

    const int n4 = out_size / 4;           // 14,112,000 float4s

    if (ws_ok) {
        hipLaunchKernelGGL((fused_kernel<0>), dim3(NBLOCKS), dim3(256), 0, stream,
                           waveform, white, out, gmax, blockmax);
        hipLaunchKernelGGL(reduce_max_kernel, dim3(1), dim3(256), 0, stream,
                           blockmax, gmax);
    } else {
        hipLaunchKernelGGL(init_max_kernel, dim3(1), dim3(1), 0, stream, gmax);
        hipLaunchKernelGGL((fused_kernel<1>), dim3(NBLOCKS), dim3(256), 0, stream,
                           waveform, white, out, gmax, blockmax);
    }
    hipLaunchKernelGGL(scale_kernel, dim3(3072), dim3(256), 0, stream,
                       out, gmax, n4);
}